// Round 12
// baseline (184.379 us; speedup 1.0000x reference)
//
#include <hip/hip_runtime.h>
#include <math.h>
#include <stdint.h>

#define ALPHA 0.2f

typedef __attribute__((ext_vector_type(8)))  short bf16x8;
typedef __attribute__((ext_vector_type(4)))  float f32x4;
typedef __attribute__((ext_vector_type(16))) float f32x16;

__device__ __forceinline__ uint32_t pack_bf16(float a, float b) {
    return ((__float_as_uint(a) + 0x8000u) >> 16) |
           ((__float_as_uint(b) + 0x8000u) & 0xFFFF0000u);
}

// ---------------------------------------------------------------------------
// Kernel 1: k_pre — fused k_wh + k_adjb (block-branched grid). Verified
// passing (rounds 3-11). Unchanged.
// ---------------------------------------------------------------------------
__global__ __launch_bounds__(512) void k_pre(const float* __restrict__ x,
                                             const float* __restrict__ W,
                                             const float* __restrict__ a,
                                             const float* __restrict__ adj,
                                             uint4* __restrict__ Whf,
                                             float* __restrict__ Wh1,
                                             float* __restrict__ Wh2,
                                             unsigned char* __restrict__ adjq) {
    __shared__ float xs[16 * 512];        // 32 KB
    __shared__ float Wv[128 * 68];        // 34.8 KB

    if (blockIdx.x >= 512) {
        // ---- adjb part: 256 blocks x 512 threads, idx 0..131071 ----
        int idx = (blockIdx.x - 512) * 512 + threadIdx.x;
        int i   = idx >> 7;
        int pos = idx & 127;                            // jg
        const float4* a4 = (const float4*)adj + idx * 2;
        float4 v0 = a4[0], v1 = a4[1];
        unsigned int by = 0;
        by |= (v0.x > 0.f) ? 1u : 0u;
        by |= (v0.y > 0.f) ? 2u : 0u;
        by |= (v0.z > 0.f) ? 4u : 0u;
        by |= (v0.w > 0.f) ? 8u : 0u;
        by |= (v1.x > 0.f) ? 16u : 0u;
        by |= (v1.y > 0.f) ? 32u : 0u;
        by |= (v1.z > 0.f) ? 64u : 0u;
        by |= (v1.w > 0.f) ? 128u : 0u;
        adjq[(i << 7) + ((pos & 1) << 6) + (((pos >> 1) & 1) << 5) + (pos >> 2)] =
            (unsigned char)by;
        return;
    }

    // ---- wh part ----
    const int tid = threadIdx.x;
    const int b   = blockIdx.x & 7;
    const int jt  = blockIdx.x >> 3;      // 0..63 (16-row tiles)

    const float4* xg4 = (const float4*)(x + (size_t)(b * 1024 + jt * 16) * 512);
    #pragma unroll
    for (int i = 0; i < 4; ++i) {
        int    idx = tid + i * 512;       // 0..2047
        float4 v   = xg4[idx];
        int jl  = idx >> 7;
        int rem = idx & 127;
        int f   = rem >> 1;
        int tq  = rem & 1;
        int kk  = f ^ ((jl >> 2) << 2);
        float* dst = &xs[jl * 512 + (tq * 4) * 64 + kk];
        dst[0]   = v.x;
        dst[64]  = v.y;
        dst[128] = v.z;
        dst[192] = v.w;
    }
    const float4* Wg4 = (const float4*)W;
    #pragma unroll
    for (int i = 0; i < 4; ++i) {
        int    idx = tid + i * 512;       // 0..2047
        float4 v   = Wg4[idx];
        int k  = idx >> 5;
        int o0 = (idx & 31) * 4;
        #pragma unroll
        for (int c = 0; c < 4; ++c) {
            int o   = o0 + c;
            int adr = o * 68 + ((((k >> 2) ^ ((o >> 3) & 7)) << 2) | (k & 3));
            Wv[adr] = (&v.x)[c];
        }
    }
    __syncthreads();

    const int w  = tid >> 6;              // wave = t (0..7)
    const int l  = tid & 63;
    const int q  = l >> 4;
    const int om = l & 15;
    const int t  = w;

    float acc[4][8];
    #pragma unroll
    for (int jj = 0; jj < 4; ++jj)
        #pragma unroll
        for (int nt = 0; nt < 8; ++nt) acc[jj][nt] = 0.f;

    for (int kc = 0; kc < 64; kc += 4) {
        float4 xv[4], wv[8];
        const int kx = kc ^ (q << 2);
        #pragma unroll
        for (int jj = 0; jj < 4; ++jj)
            xv[jj] = *(const float4*)&xs[(q * 4 + jj) * 512 + t * 64 + kx];
        #pragma unroll
        for (int nt = 0; nt < 8; ++nt) {
            int og  = nt * 16 + om;
            int grp = (kc >> 2) ^ ((nt * 2 + (om >> 3)) & 7);
            wv[nt]  = *(const float4*)&Wv[og * 68 + grp * 4];
        }
        #pragma unroll
        for (int jj = 0; jj < 4; ++jj) {
            #pragma unroll
            for (int nt = 0; nt < 8; ++nt) {
                float s = acc[jj][nt];
                s = fmaf(xv[jj].x, wv[nt].x, s);
                s = fmaf(xv[jj].y, wv[nt].y, s);
                s = fmaf(xv[jj].z, wv[nt].z, s);
                s = fmaf(xv[jj].w, wv[nt].w, s);
                acc[jj][nt] = s;
            }
        }
    }

    const int bt = b * 8 + t;

    float a1v[8], a2v[8];
    #pragma unroll
    for (int nt = 0; nt < 8; ++nt) {
        a1v[nt] = a[nt * 16 + om];
        a2v[nt] = a[128 + nt * 16 + om];
    }
    #pragma unroll
    for (int jj = 0; jj < 4; ++jj) {
        float s1 = 0.f, s2 = 0.f;
        #pragma unroll
        for (int nt = 0; nt < 8; ++nt) {
            s1 = fmaf(acc[jj][nt], a1v[nt], s1);
            s2 = fmaf(acc[jj][nt], a2v[nt], s2);
        }
        #pragma unroll
        for (int off = 1; off < 16; off <<= 1) {
            s1 += __shfl_xor(s1, off);
            s2 += __shfl_xor(s2, off);
        }
        if (om == 0) {
            int j = jt * 16 + q * 4 + jj;
            Wh1[bt * 1024 + j] = s1;
            Wh2[bt * 1024 + j] = s2;
        }
    }

    // 32x32x16 B-frag store
    #pragma unroll
    for (int nt = 0; nt < 8; ++nt) {
        uint2 st;
        st.x = pack_bf16(acc[0][nt], acc[1][nt]);
        st.y = pack_bf16(acc[2][nt], acc[3][nt]);
        int    lane2 = ((q >> 1) << 5) | ((nt & 1) << 4) | om;
        size_t fidx  = ((size_t)(bt * 4 + (nt >> 1)) * 64 + jt) * 64 + lane2;
        char*  p     = (char*)(Whf + fidx) + ((q & 1) << 3);
        *(uint2*)p = st;
    }
}

// ---------------------------------------------------------------------------
// Kernel 2: k_agg — ROUND-21: phase-decorrelation at 1x work.
//   Evidence r6-r11: ~52 us across 3 tilings while busy time ~16-23 us;
//   always 2 barrier-synced blocks/CU launched in phase -> correlated
//   stalls. r8 (o-split) doubled P-build; r11 (j-split) gained no occupancy
//   (reg cap 168 -> 3 waves/SIMD) and added work. This round: SAME r7
//   dataflow, re-tiled to 2-WAVE blocks (128 thr), grid 1024: 64 i-rows x
//   full 128 o-cols; wave w2 owns rows w2*32..+32 -> P-build exactly once
//   per (row,j). bstage single-buffered (16 KB) with barrier-write-barrier
//   per superstep; pf[8] issued a FULL superstep ahead so the vmcnt wait at
//   ds_write is pre-satisfied. LDS 24.6 KB -> 6 independent blocks/CU =
//   12 waves/CU (vs 8 in 2 correlated blocks). Only E/F staging + Whf
//   re-reads duplicate (16 itiles/plane, L2-served).
//   Index map (verified r7 formulas): slot = ntile*4+(f&3), ntile =
//   w2*2+(f>>2); pe = (ts&1)*32+(v>>1)*4+(v&1)*2+(ts>>1); jb = v*64+ts*16+g*8.
//   Register history (DO NOT re-litigate): launch-bounds minima and
//   gload_lds all spilled (r10/r12/r13/r14); pf-reg + ds_write staging only.
//   RULE #20: every acc/accl/pf/am access uses a compile-time index.
// Layouts: A idx=lane&31, k=(lane>>5)*8+e; D col=lane&31,
// row=(reg&3)+8*(reg>>2)+4*(lane>>5); l_i via ones-MFMA.
// Grid 1024: blockIdx = ((itile*8 + t)*8 + b), itile 0..15 -> XCD = b.
// ---------------------------------------------------------------------------
__global__ __launch_bounds__(128) void k_agg(const uint4* __restrict__ Whf,
                                             const float* __restrict__ Wh1,
                                             const float* __restrict__ Wh2,
                                             const unsigned char* __restrict__ adjq,
                                             float* __restrict__ out) {
    __shared__ __attribute__((aligned(16))) uint4 bstage[16][64];   // 16 KB
    __shared__ __attribute__((aligned(16))) float efs[2][1024];     // 8 KB
    __shared__ float m2s[2];

    const int tid   = threadIdx.x;
    const int b     = blockIdx.x & 7;
    const int t     = (blockIdx.x >> 3) & 7;
    const int itile = blockIdx.x >> 6;            // 0..15
    const int bt    = b * 8 + t;
    const int i0    = itile * 64;

    const int w2  = tid >> 6;                     // wave 0..1
    const int l   = tid & 63;
    const int col = l & 31;
    const int g   = l >> 5;                       // k-half group
    const int row = w2 * 32 + col;                // block-local i-row

    const uint4* plane = Whf + (size_t)bt * 16384;

    // prefetch superstep 0: wave w2 owns ntiles {2w2, 2w2+1}, 4 slots each
    uint4 pf[8];
    #pragma unroll
    for (int f = 0; f < 8; ++f)
        pf[f] = plane[((w2 * 2 + (f >> 2)) * 64 + (f & 3)) * 64 + l];

    // adj mask regs: 64 B at (i0+row)*128 + g*64
    const uint4* ap = (const uint4*)(adjq + ((size_t)(i0 + row) << 7) + (g << 6));
    uint4 am[4];
    #pragma unroll
    for (int f = 0; f < 4; ++f) am[f] = ap[f];

    // stage E/F (full 1024 j) + running max of h2; h1 direct per-thread
    const float* wh2g = Wh2 + bt * 1024;
    float mx = -1e30f;
    #pragma unroll
    for (int rep = 0; rep < 8; ++rep) {
        int   j  = tid + rep * 128;
        float h2 = wh2g[j];
        efs[0][j] = __expf(h2);
        efs[1][j] = __expf(ALPHA * h2);
        mx = fmaxf(mx, h2);
    }
    #pragma unroll
    for (int off = 1; off < 64; off <<= 1) mx = fmaxf(mx, __shfl_xor(mx, off));
    if (l == 0) m2s[w2] = mx;
    const float h1 = Wh1[bt * 1024 + i0 + row];

    // stage superstep 0 (vmcnt wait on pf inserted by compiler)
    #pragma unroll
    for (int f = 0; f < 8; ++f)
        bstage[(w2 * 2 + (f >> 2)) * 4 + (f & 3)][l] = pf[f];
    __syncthreads();                              // B0: m2s + buf staged

    const float M2 = fmaxf(m2s[0], m2s[1]);
    const float e0 = h1 + M2;
    const float mp = fmaxf(e0, ALPHA * e0);       // both products <= 1
    const float Af = __expf(h1 - mp);
    const float Bf = __expf(ALPHA * h1 - mp);

    // issue prefetch for superstep 1 (a full superstep of cover)
    #pragma unroll
    for (int f = 0; f < 8; ++f)
        pf[f] = plane[((w2 * 2 + (f >> 2)) * 64 + 4 + (f & 3)) * 64 + l];

    f32x16 acc[4];
    #pragma unroll
    for (int nt2 = 0; nt2 < 4; ++nt2)
        #pragma unroll
        for (int r = 0; r < 16; ++r) acc[nt2][r] = 0.f;
    f32x16 accl;
    #pragma unroll
    for (int r = 0; r < 16; ++r) accl[r] = 0.f;

    bf16x8 ones;
    #pragma unroll
    for (int i = 0; i < 8; ++i) ones[i] = (short)0x3F80;

    #pragma unroll
    for (int v = 0; v < 16; ++v) {
        #pragma unroll
        for (int ts = 0; ts < 4; ++ts) {          // 16-j MFMA slice
            const int jb = v * 64 + ts * 16 + g * 8;
            float4 E0 = *(const float4*)&efs[0][jb];
            float4 E1 = *(const float4*)&efs[0][jb + 4];
            float4 F0 = *(const float4*)&efs[1][jb];
            float4 F1 = *(const float4*)&efs[1][jb + 4];

            // adj byte (static select after full unroll)
            const int      pe = (ts & 1) * 32 + (v >> 1) * 4 + (v & 1) * 2 + (ts >> 1);
            const uint4    av = am[pe >> 4];
            const int      cc = (pe >> 2) & 3;
            const uint32_t cw = (cc == 0) ? av.x : (cc == 1) ? av.y
                               : (cc == 2) ? av.z : av.w;
            const uint32_t by = (cw >> ((pe & 3) * 8)) & 0xFFu;

            float p[8];
            p[0] = fmaxf(Af * E0.x, Bf * F0.x) * (float)((by >> 0) & 1u);
            p[1] = fmaxf(Af * E0.y, Bf * F0.y) * (float)((by >> 1) & 1u);
            p[2] = fmaxf(Af * E0.z, Bf * F0.z) * (float)((by >> 2) & 1u);
            p[3] = fmaxf(Af * E0.w, Bf * F0.w) * (float)((by >> 3) & 1u);
            p[4] = fmaxf(Af * E1.x, Bf * F1.x) * (float)((by >> 4) & 1u);
            p[5] = fmaxf(Af * E1.y, Bf * F1.y) * (float)((by >> 5) & 1u);
            p[6] = fmaxf(Af * E1.z, Bf * F1.z) * (float)((by >> 6) & 1u);
            p[7] = fmaxf(Af * E1.w, Bf * F1.w) * (float)((by >> 7) & 1u);

            union { uint32_t u32[4]; bf16x8 v8; } pk;
            #pragma unroll
            for (int r = 0; r < 4; ++r)
                pk.u32[r] = pack_bf16(p[2 * r], p[2 * r + 1]);

            #pragma unroll
            for (int nt2 = 0; nt2 < 4; ++nt2) {
                union { uint4 u4; bf16x8 v8; } br;
                br.u4 = bstage[nt2 * 4 + ts][l];
                acc[nt2] = __builtin_amdgcn_mfma_f32_32x32x16_bf16(
                    pk.v8, br.v8, acc[nt2], 0, 0, 0);
            }
            accl = __builtin_amdgcn_mfma_f32_32x32x16_bf16(
                pk.v8, ones, accl, 0, 0, 0);
        }

        if (v < 15) {
            __syncthreads();                      // Ba: all reads of buf done
            #pragma unroll
            for (int f = 0; f < 8; ++f)
                bstage[(w2 * 2 + (f >> 2)) * 4 + (f & 3)][l] = pf[f];
            __syncthreads();                      // Bb: next superstep staged
            if (v + 2 < 16) {
                #pragma unroll
                for (int f = 0; f < 8; ++f)
                    pf[f] = plane[((w2 * 2 + (f >> 2)) * 64 + (v + 2) * 4 + (f & 3)) * 64 + l];
            }
        }
    }

    // epilogue: D rows r = (reg&3)+8*(reg>>2)+4*g; accl rows identical
    float* og = out + ((size_t)(b * 1024 + i0 + w2 * 32)) * 1024 + t;
    #pragma unroll
    for (int reg = 0; reg < 16; ++reg) {
        const int   r    = (reg & 3) + 8 * (reg >> 2) + 4 * g;
        const float linv = 1.0f / accl[reg];
        #pragma unroll
        for (int nt2 = 0; nt2 < 4; ++nt2) {
            float vv = acc[nt2][reg] * linv;
            vv = vv > 0.f ? vv : __expf(vv) - 1.f;
            og[(size_t)r * 1024 + (nt2 * 32 + col) * 8] = vv;
        }
    }
}

// ---------------------------------------------------------------------------
extern "C" void kernel_launch(void* const* d_in, const int* in_sizes, int n_in,
                              void* d_out, int out_size, void* d_ws, size_t ws_size,
                              hipStream_t stream) {
    const float* x   = (const float*)d_in[0];   // (8,1024,64,8)
    const float* adj = (const float*)d_in[1];   // (1024,1024)
    const float* W   = (const float*)d_in[2];   // (64,128)
    const float* a   = (const float*)d_in[3];   // (256,1)
    float* out = (float*)d_out;                 // (8,1024,128,8)

    uint4*         Whf  = (uint4*)d_ws;                        // 1048576 uint4 = 16 MB
    float*         Wh1  = (float*)(Whf + 1048576);             // 65536 f
    float*         Wh2  = Wh1 + 65536;                         // 65536 f
    unsigned char* adjq = (unsigned char*)(Wh2 + 65536);       // 131072 B

    k_pre<<<768, 512, 0, stream>>>(x, W, a, adj, Whf, Wh1, Wh2, adjq);
    k_agg<<<1024, 128, 0, stream>>>(Whf, Wh1, Wh2, adjq, out);
}

// Round 13
// 135.095 us; speedup vs baseline: 1.3648x; 1.3648x over previous
//
#include <hip/hip_runtime.h>
#include <math.h>
#include <stdint.h>

#define ALPHA 0.2f

typedef __attribute__((ext_vector_type(8)))  short bf16x8;
typedef __attribute__((ext_vector_type(4)))  float f32x4;
typedef __attribute__((ext_vector_type(16))) float f32x16;

__device__ __forceinline__ uint32_t pack_bf16(float a, float b) {
    return ((__float_as_uint(a) + 0x8000u) >> 16) |
           ((__float_as_uint(b) + 0x8000u) & 0xFFFF0000u);
}
__device__ __forceinline__ unsigned short bf16_1(float a) {
    return (unsigned short)((__float_as_uint(a) + 0x8000u) >> 16);
}

// ---------------------------------------------------------------------------
// Kernel 1: k_pre — ROUND-22 REWRITE: wh-part now bf16 MFMA GEMM.
//   Rationale: total ≈ 88us + k_agg across all clean rounds -> k_pre ≈ 35-52
//   us vs a ~10us VALU / 0.5us MFMA floor (1.07 GFLOP). The old fp32 scalar
//   FMA loop (2048 MACs/thread) is replaced by 16 mfma_f32_32x32x16_bf16
//   per wave on bf16-cast x/W staged in LDS.
//   Blocks 0..511: (b = blk&7, jt32 = (blk>>3)&31, th = blk>>8); 4 waves =
//   t = th*4 + w. LDS: xbf[4][32][64] bf16 (16 KB) + Wbf[128][64] bf16
//   transposed (16 KB), both XOR-swizzled (byte ^= (row&7)<<4, G4) so the
//   stride-128B A/B frag reads are ~4-way instead of 32-way conflicted.
//   A-frag (x^T): m=j=lane&31, k=f=(lane>>5)*8+e; B-frag (W): n=o=lane&31,
//   same k. D: col=o=lane&31, row=j=(reg&3)+8*(reg>>2)+4*(lane>>5).
//   D -> Whf B-frag in-register: per 32x32 D-tile, 8 pack_bf16 + 8
//   shfl_xor(32) + cndmask; byte-layout equivalence with the old verified
//   store checked element-wise (w0@g=0 = j{0,1} etc).
//   Wh1/Wh2 from fp32 D accs: per-reg dot with a1/a2 + 5-step shfl reduce
//   over the 32-lane half; lanes col==0 write.
//   Precision: inputs now bf16-rounded once (was fp32 exact) -> absmax
//   expected ~0.1-0.15 vs 0.18375 threshold. DECLARED RISK.
//   Blocks 512..1023: adjb (idx = (blk-512)*256 + tid, unchanged formula).
//   RULE #20: all acc/pk indices compile-time.
// ---------------------------------------------------------------------------
__global__ __launch_bounds__(256) void k_pre(const float* __restrict__ x,
                                             const float* __restrict__ W,
                                             const float* __restrict__ a,
                                             const float* __restrict__ adj,
                                             uint4* __restrict__ Whf,
                                             float* __restrict__ Wh1,
                                             float* __restrict__ Wh2,
                                             unsigned char* __restrict__ adjq) {
    __shared__ __attribute__((aligned(16))) unsigned short xbf[4 * 32 * 64]; // 16 KB
    __shared__ __attribute__((aligned(16))) unsigned short Wbf[128 * 64];    // 16 KB

    if (blockIdx.x >= 512) {
        // ---- adjb part: 512 blocks x 256 threads, idx 0..131071 ----
        int idx = (blockIdx.x - 512) * 256 + threadIdx.x;
        int i   = idx >> 7;
        int pos = idx & 127;                            // jg
        const float4* a4 = (const float4*)adj + idx * 2;
        float4 v0 = a4[0], v1 = a4[1];
        unsigned int by = 0;
        by |= (v0.x > 0.f) ? 1u : 0u;
        by |= (v0.y > 0.f) ? 2u : 0u;
        by |= (v0.z > 0.f) ? 4u : 0u;
        by |= (v0.w > 0.f) ? 8u : 0u;
        by |= (v1.x > 0.f) ? 16u : 0u;
        by |= (v1.y > 0.f) ? 32u : 0u;
        by |= (v1.z > 0.f) ? 64u : 0u;
        by |= (v1.w > 0.f) ? 128u : 0u;
        adjq[(i << 7) + ((pos & 1) << 6) + (((pos >> 1) & 1) << 5) + (pos >> 2)] =
            (unsigned char)by;
        return;
    }

    const int tid  = threadIdx.x;
    const int b    = blockIdx.x & 7;
    const int jt32 = (blockIdx.x >> 3) & 31;      // 32-row j-tile
    const int th   = blockIdx.x >> 8;             // t-half 0/1

    // ---- stage x: 32j x 64f x 4t fp32 -> bf16 LDS [t_loc][j][f], swizzled
    const float* xg = x + ((size_t)(b * 1024 + jt32 * 32) * 64) * 8 + th * 4;
    #pragma unroll
    for (int i = 0; i < 8; ++i) {
        int idx = tid + i * 256;                  // 0..2047
        int j   = idx >> 6;
        int f   = idx & 63;
        float4 v = *(const float4*)(xg + (size_t)(j * 64 + f) * 8);
        const int sw = ((j & 7) << 4);
        *(unsigned short*)((char*)xbf + ((((0 * 32 + j) * 64 + f) * 2) ^ sw)) = bf16_1(v.x);
        *(unsigned short*)((char*)xbf + ((((1 * 32 + j) * 64 + f) * 2) ^ sw)) = bf16_1(v.y);
        *(unsigned short*)((char*)xbf + ((((2 * 32 + j) * 64 + f) * 2) ^ sw)) = bf16_1(v.z);
        *(unsigned short*)((char*)xbf + ((((3 * 32 + j) * 64 + f) * 2) ^ sw)) = bf16_1(v.w);
    }
    // ---- stage W: 64f x 128o fp32 -> bf16 LDS [o][f] (transposed), swizzled
    const float4* Wg4 = (const float4*)W;
    #pragma unroll
    for (int i = 0; i < 8; ++i) {
        int idx = tid + i * 256;                  // 0..2047
        int fr  = idx >> 5;
        int o0  = (idx & 31) * 4;
        float4 v = Wg4[idx];
        #pragma unroll
        for (int c = 0; c < 4; ++c) {
            int o = o0 + c;
            *(unsigned short*)((char*)Wbf + (((o * 64 + fr) * 2) ^ ((o & 7) << 4))) =
                bf16_1((&v.x)[c]);
        }
    }
    __syncthreads();

    const int w   = tid >> 6;                     // wave 0..3
    const int l   = tid & 63;
    const int col = l & 31;
    const int g   = l >> 5;
    const int t   = th * 4 + w;
    const int bt  = b * 8 + t;

    f32x16 acc[4];
    #pragma unroll
    for (int nt2 = 0; nt2 < 4; ++nt2)
        #pragma unroll
        for (int r = 0; r < 16; ++r) acc[nt2][r] = 0.f;

    // ---- 16 MFMA: D[32j x 32o] x4 o-tiles, K=64 in 4 steps of 16
    #pragma unroll
    for (int kk = 0; kk < 4; ++kk) {
        union { uint4 u4; bf16x8 v8; } av;
        const int abyte = (((w * 32 + col) * 64 + kk * 16 + g * 8) * 2) ^ ((col & 7) << 4);
        av.u4 = *(const uint4*)((const char*)xbf + abyte);
        #pragma unroll
        for (int nt2 = 0; nt2 < 4; ++nt2) {
            union { uint4 u4; bf16x8 v8; } bv;
            const int o     = nt2 * 32 + col;
            const int bbyte = ((o * 64 + kk * 16 + g * 8) * 2) ^ ((o & 7) << 4);
            bv.u4 = *(const uint4*)((const char*)Wbf + bbyte);
            acc[nt2] = __builtin_amdgcn_mfma_f32_32x32x16_bf16(
                av.v8, bv.v8, acc[nt2], 0, 0, 0);
        }
    }

    // ---- Wh1/Wh2: per-reg dot over o (in-thread over 4 tiles + 32-lane reduce)
    float a1v[4], a2v[4];
    #pragma unroll
    for (int nt2 = 0; nt2 < 4; ++nt2) {
        a1v[nt2] = a[nt2 * 32 + col];
        a2v[nt2] = a[128 + nt2 * 32 + col];
    }
    #pragma unroll
    for (int reg = 0; reg < 16; ++reg) {
        float s1 = acc[0][reg] * a1v[0] + acc[1][reg] * a1v[1]
                 + acc[2][reg] * a1v[2] + acc[3][reg] * a1v[3];
        float s2 = acc[0][reg] * a2v[0] + acc[1][reg] * a2v[1]
                 + acc[2][reg] * a2v[2] + acc[3][reg] * a2v[3];
        #pragma unroll
        for (int off = 1; off < 32; off <<= 1) {
            s1 += __shfl_xor(s1, off);
            s2 += __shfl_xor(s2, off);
        }
        if (col == 0) {
            int j = jt32 * 32 + (reg & 3) + 8 * (reg >> 2) + 4 * g;
            Wh1[bt * 1024 + j] = s1;
            Wh2[bt * 1024 + j] = s2;
        }
    }

    // ---- D -> Whf B-frag conversion + store (layout matches old verified
    //      store: lane holds o=l&31, j=(l>>5)*8+e within each 16-j subtile)
    #pragma unroll
    for (int nt2 = 0; nt2 < 4; ++nt2) {
        const uint32_t pk0 = pack_bf16(acc[nt2][0],  acc[nt2][1]);
        const uint32_t pk1 = pack_bf16(acc[nt2][2],  acc[nt2][3]);
        const uint32_t pk2 = pack_bf16(acc[nt2][4],  acc[nt2][5]);
        const uint32_t pk3 = pack_bf16(acc[nt2][6],  acc[nt2][7]);
        const uint32_t pk4 = pack_bf16(acc[nt2][8],  acc[nt2][9]);
        const uint32_t pk5 = pack_bf16(acc[nt2][10], acc[nt2][11]);
        const uint32_t pk6 = pack_bf16(acc[nt2][12], acc[nt2][13]);
        const uint32_t pk7 = pack_bf16(acc[nt2][14], acc[nt2][15]);
        const uint32_t xp0 = __shfl_xor(pk0, 32);
        const uint32_t xp1 = __shfl_xor(pk1, 32);
        const uint32_t xp2 = __shfl_xor(pk2, 32);
        const uint32_t xp3 = __shfl_xor(pk3, 32);
        const uint32_t xp4 = __shfl_xor(pk4, 32);
        const uint32_t xp5 = __shfl_xor(pk5, 32);
        const uint32_t xp6 = __shfl_xor(pk6, 32);
        const uint32_t xp7 = __shfl_xor(pk7, 32);
        const bool gh = (g != 0);

        uint4 s0, s1q;
        s0.x  = gh ? xp2 : pk0;   // jsub0: e0,e1
        s0.y  = gh ? xp3 : pk1;   //        e2,e3
        s0.z  = gh ? pk2 : xp0;   //        e4,e5
        s0.w  = gh ? pk3 : xp1;   //        e6,e7
        s1q.x = gh ? xp6 : pk4;   // jsub1
        s1q.y = gh ? xp7 : pk5;
        s1q.z = gh ? pk6 : xp4;
        s1q.w = gh ? pk7 : xp5;

        const size_t base = ((size_t)(bt * 4 + nt2) * 64 + jt32 * 2) * 64 + l;
        Whf[base]      = s0;      // jt16 = jt32*2
        Whf[base + 64] = s1q;     // jt16 = jt32*2 + 1
    }
}

// ---------------------------------------------------------------------------
// Kernel 2: k_agg — EXACT round-7 version (52.5 us verified; 76 VGPR, zero
// scratch, LDS 41 KB, 16 supersteps of 64 j, pf[4]+ds_write dbuf staging).
// k_agg restructuring is CLOSED: r8 o-split (2x P-build, 63us), r11 j-split
// (no occupancy gain at 168 regs, 67.5us), r12 128-thr retile (spill,
// 97us), plus r10/r12/r13/r14 launch-bounds/gload spills. ~170-reg live set
// pins 3 waves/SIMD; latency floor ~52us stands.
// Layouts: A idx=lane&31, k=(lane>>5)*8+e; D col=lane&31,
// row=(reg&3)+8*(reg>>2)+4*(lane>>5); l_i via ones-MFMA.
// Grid 512: blockIdx = ((itile*8 + t)*8 + b) -> XCD = b.
// ---------------------------------------------------------------------------
__global__ __launch_bounds__(256) void k_agg(const uint4* __restrict__ Whf,
                                             const float* __restrict__ Wh1,
                                             const float* __restrict__ Wh2,
                                             const unsigned char* __restrict__ adjq,
                                             float* __restrict__ out) {
    __shared__ __attribute__((aligned(16))) uint4 bstage[2][1024];  // 32 KB
    __shared__ __attribute__((aligned(16))) float efsE[1024];       // 4 KB
    __shared__ __attribute__((aligned(16))) float efsF[1024];       // 4 KB
    __shared__ float m2s[4];

    const int tid   = threadIdx.x;
    const int b     = blockIdx.x & 7;
    const int t     = (blockIdx.x >> 3) & 7;
    const int itile = blockIdx.x >> 6;            // 0..7
    const int bt    = b * 8 + t;
    const int i0    = itile * 128;

    const int w   = tid >> 6;                     // wave 0..3 (= ntile chunk)
    const int l   = tid & 63;
    const int col = l & 31;
    const int g   = l >> 5;                       // k-half group
    const int row = w * 32 + col;                 // block-local i-row

    const uint4* plane = Whf + (size_t)bt * 16384;

    // prefetch superstep 0 (kf 0..3 of this wave's ntile chunk)
    uint4 pf[4];
    #pragma unroll
    for (int f = 0; f < 4; ++f) pf[f] = plane[(w * 64 + f) * 64 + l];

    // adj mask regs: 64 B at (i0+row)*128 + g*64
    const uint4* ap = (const uint4*)(adjq + ((size_t)(i0 + row) << 7) + (g << 6));
    uint4 am[4];
    #pragma unroll
    for (int f = 0; f < 4; ++f) am[f] = ap[f];

    // stage E/F (separate fp32) + running max of h2; h1 direct per-thread
    const float* wh2g = Wh2 + bt * 1024;
    float mx = -1e30f;
    #pragma unroll
    for (int rep = 0; rep < 4; ++rep) {
        int   j  = tid + rep * 256;
        float h2 = wh2g[j];
        efsE[j] = __expf(h2);
        efsF[j] = __expf(ALPHA * h2);
        mx = fmaxf(mx, h2);
    }
    #pragma unroll
    for (int off = 1; off < 64; off <<= 1) mx = fmaxf(mx, __shfl_xor(mx, off));
    if (l == 0) m2s[w] = mx;
    const float h1 = Wh1[bt * 1024 + i0 + row];

    #pragma unroll
    for (int f = 0; f < 4; ++f) bstage[0][(w * 4 + f) * 64 + l] = pf[f];
    __syncthreads();

    const float M2 = fmaxf(fmaxf(m2s[0], m2s[1]), fmaxf(m2s[2], m2s[3]));
    const float e0 = h1 + M2;
    const float mp = fmaxf(e0, ALPHA * e0);       // both products <= 1
    const float Af = __expf(h1 - mp);
    const float Bf = __expf(ALPHA * h1 - mp);

    f32x16 acc[4];
    #pragma unroll
    for (int nt2 = 0; nt2 < 4; ++nt2)
        #pragma unroll
        for (int r = 0; r < 16; ++r) acc[nt2][r] = 0.f;
    f32x16 accl;
    #pragma unroll
    for (int r = 0; r < 16; ++r) accl[r] = 0.f;

    bf16x8 ones;
    #pragma unroll
    for (int i = 0; i < 8; ++i) ones[i] = (short)0x3F80;

    #pragma unroll
    for (int v = 0; v < 16; ++v) {
        if (v + 1 < 16) {
            #pragma unroll
            for (int f = 0; f < 4; ++f)
                pf[f] = plane[(w * 64 + (v + 1) * 4 + f) * 64 + l];
        }

        #pragma unroll
        for (int ts = 0; ts < 4; ++ts) {          // 16-j MFMA slice
            const int jb = v * 64 + ts * 16 + g * 8;
            float4 E0 = *(const float4*)&efsE[jb];
            float4 E1 = *(const float4*)&efsE[jb + 4];
            float4 F0 = *(const float4*)&efsF[jb];
            float4 F1 = *(const float4*)&efsF[jb + 4];

            // adj byte (static select after full unroll)
            const int      pe = (ts & 1) * 32 + (v >> 1) * 4 + (v & 1) * 2 + (ts >> 1);
            const uint4    av = am[pe >> 4];
            const int      cc = (pe >> 2) & 3;
            const uint32_t cw = (cc == 0) ? av.x : (cc == 1) ? av.y
                               : (cc == 2) ? av.z : av.w;
            const uint32_t by = (cw >> ((pe & 3) * 8)) & 0xFFu;

            float p[8];
            p[0] = fmaxf(Af * E0.x, Bf * F0.x) * (float)((by >> 0) & 1u);
            p[1] = fmaxf(Af * E0.y, Bf * F0.y) * (float)((by >> 1) & 1u);
            p[2] = fmaxf(Af * E0.z, Bf * F0.z) * (float)((by >> 2) & 1u);
            p[3] = fmaxf(Af * E0.w, Bf * F0.w) * (float)((by >> 3) & 1u);
            p[4] = fmaxf(Af * E1.x, Bf * F1.x) * (float)((by >> 4) & 1u);
            p[5] = fmaxf(Af * E1.y, Bf * F1.y) * (float)((by >> 5) & 1u);
            p[6] = fmaxf(Af * E1.z, Bf * F1.z) * (float)((by >> 6) & 1u);
            p[7] = fmaxf(Af * E1.w, Bf * F1.w) * (float)((by >> 7) & 1u);

            union { uint32_t u32[4]; bf16x8 v8; } pk;
            #pragma unroll
            for (int r = 0; r < 4; ++r)
                pk.u32[r] = pack_bf16(p[2 * r], p[2 * r + 1]);

            #pragma unroll
            for (int nt2 = 0; nt2 < 4; ++nt2) {
                union { uint4 u4; bf16x8 v8; } br;
                br.u4 = bstage[v & 1][(nt2 * 4 + ts) * 64 + l];
                acc[nt2] = __builtin_amdgcn_mfma_f32_32x32x16_bf16(
                    pk.v8, br.v8, acc[nt2], 0, 0, 0);
            }
            accl = __builtin_amdgcn_mfma_f32_32x32x16_bf16(
                pk.v8, ones, accl, 0, 0, 0);
        }

        if (v + 1 < 16) {
            #pragma unroll
            for (int f = 0; f < 4; ++f)
                bstage[(v + 1) & 1][(w * 4 + f) * 64 + l] = pf[f];
        }
        __syncthreads();
    }

    // epilogue: D rows r = (reg&3)+8*(reg>>2)+4*g; accl rows identical
    float* og = out + ((size_t)(b * 1024 + i0 + w * 32)) * 1024 + t;
    #pragma unroll
    for (int reg = 0; reg < 16; ++reg) {
        const int   r    = (reg & 3) + 8 * (reg >> 2) + 4 * g;
        const float linv = 1.0f / accl[reg];
        #pragma unroll
        for (int nt2 = 0; nt2 < 4; ++nt2) {
            float vv = acc[nt2][reg] * linv;
            vv = vv > 0.f ? vv : __expf(vv) - 1.f;
            og[(size_t)r * 1024 + (nt2 * 32 + col) * 8] = vv;
        }
    }
}

// ---------------------------------------------------------------------------
extern "C" void kernel_launch(void* const* d_in, const int* in_sizes, int n_in,
                              void* d_out, int out_size, void* d_ws, size_t ws_size,
                              hipStream_t stream) {
    const float* x   = (const float*)d_in[0];   // (8,1024,64,8)
    const float* adj = (const float*)d_in[1];   // (1024,1024)
    const float* W   = (const float*)d_in[2];   // (64,128)
    const float* a   = (const float*)d_in[3];   // (256,1)
    float* out = (float*)d_out;                 // (8,1024,128,8)

    uint4*         Whf  = (uint4*)d_ws;                        // 1048576 uint4 = 16 MB
    float*         Wh1  = (float*)(Whf + 1048576);             // 65536 f
    float*         Wh2  = Wh1 + 65536;                         // 65536 f
    unsigned char* adjq = (unsigned char*)(Wh2 + 65536);       // 131072 B

    k_pre<<<1024, 256, 0, stream>>>(x, W, a, adj, Whf, Wh1, Wh2, adjq);
    k_agg<<<512, 256, 0, stream>>>(Whf, Wh1, Wh2, adjq, out);
}